// Round 11
// baseline (6574.216 us; speedup 1.0000x reference)
//
#include <hip/hip_runtime.h>
#include <stdint.h>

#define Tn 100
#define Dn 51
#define Hn 128
#define G4 512     // 4*H
#define BR 8       // batch rows per workgroup
#define NWG 256    // workgroups (2048 / 8)
#define NTH 1024   // 16 waves
#define RP 264     // xhA row stride in bf16 elems (16B-aligned rows)

typedef unsigned int uint32;
typedef unsigned short u16;
typedef short s16x8 __attribute__((ext_vector_type(8)));   // 8 bf16 = 4 VGPRs
typedef float f32x4v __attribute__((ext_vector_type(4)));

__device__ __forceinline__ float rcp_(float x){ return __builtin_amdgcn_rcpf(x); }
__device__ __forceinline__ float sigm(float x){ return rcp_(1.f + __expf(-x)); }
__device__ __forceinline__ float tanh_(float x){ return 1.f - 2.f*rcp_(1.f + __expf(2.f*x)); }

// fp32 -> bf16 round-to-nearest-even
__device__ __forceinline__ u16 f2bf(float f){
  uint32 u = __float_as_uint(f);
  return (u16)((u + 0x7fffu + ((u >> 16) & 1u)) >> 16);
}
__device__ __forceinline__ float bf2f(u16 u){ return __uint_as_float(((uint32)u)<<16); }

// A-fragment trick: row r (0..7) = bf16-hi of xh row r; row r+8 = bf16-lo.
// One MFMA computes both pumps; epilogue sums D[r] + D[r+8] via shfl.
__device__ __forceinline__ void wr_xh(u16* __restrict__ xhA, int r, int k, float v){
  u16 h = f2bf(v);
  xhA[r*RP + k]     = h;
  xhA[(r+8)*RP + k] = f2bf(v - bf2f(h));
}

struct WP {
  const float* W[6];   // [4H, din]  enc0..2, dec0..2 (fp32)
  const float* U[6];   // [4H, H]
  const float* Bb[6];  // [4H]
  const float* fW;     // [D, H]
  const float* fb;     // [D]
};

// ws: wsw = MFMA-B-fragment-swizzled bf16 weights.
// Layout per layer (uniform 131072 u16): block (n,s) at ((n*8+s)*64+lane)*8+j,
// holding Wc[k = s*32+(lane>>4)*8+j][c = n*16+(lane&15)], Wc = [Wih | Whh] along k,
// zero-padded (k>=K or s>=S). A wave's B-frag load = contiguous 1KB dwordx4.
#define PREP_TOTAL (6*131072 + 6*512 + 8192 + 64)
__global__ void prep_kernel(WP p, u16* __restrict__ wsw, float* __restrict__ bias,
                            float* __restrict__ fwt, float* __restrict__ fbw)
{
  int gid = blockIdx.x*256 + threadIdx.x;
  if (gid >= PREP_TOTAL) return;
  if (gid < 6*131072){
    int l = gid >> 17;
    int e = gid & 131071;
    int n    = e >> 12;
    int s    = (e >> 9) & 7;
    int lane = (e >> 3) & 63;
    int j    = e & 7;
    int k = s*32 + (lane >> 4)*8 + j;
    int c = n*16 + (lane & 15);
    int din = (l % 3 == 0) ? Dn : Hn;
    int K = din + Hn;
    u16 v = 0;
    if (k < K){
      float f = (k < din) ? p.W[l][(size_t)c*din + k] : p.U[l][(size_t)c*Hn + (k - din)];
      v = f2bf(f);
    }
    wsw[gid] = v;
  } else if (gid < 6*131072 + 6*512){
    int i = gid - 6*131072;
    bias[i] = p.Bb[i>>9][i & 511];
  } else if (gid < 6*131072 + 6*512 + 8192){
    int i = gid - (6*131072 + 6*512);
    int k = i >> 6, d = i & 63;
    fwt[i] = (d < Dn) ? p.fW[(size_t)d*Hn + k] : 0.f;
  } else {
    int d = gid - (6*131072 + 6*512 + 8192);
    fbw[d] = (d < Dn) ? p.fb[d] : 0.f;
  }
}

// gates[r][c] = bias[c] + sum_k xh[r][k]*Wc[k][c] via mfma_f32_16x16x32_bf16.
// Wave w owns N-tiles n=2w,2w+1. A rows 0-7 = hi, 8-15 = lo (one MFMA/both pumps).
// C/D: col=lane&15, row=(lane>>4)*4+reg (m89) -> row r in lane L<32, r+8 in L+32.
template<int S>
__device__ __forceinline__ void gemm_mfma(const u16* __restrict__ wsl,
                                          const float* __restrict__ bl,
                                          const u16* __restrict__ xhA,
                                          float* __restrict__ gates, int tid)
{
  const int wave = tid >> 6, lane = tid & 63;
  const int mrow = lane & 15, kgrp = lane >> 4;
  const int n0 = wave*2;
  const u16* bp0 = wsl + n0*4096 + lane*8;
  const int aoff = mrow*RP + kgrp*8;
  f32x4v acc0 = {0.f,0.f,0.f,0.f}, acc1 = {0.f,0.f,0.f,0.f};
  #pragma unroll
  for (int s=0; s<S; s++){
    s16x8 a  = *(const s16x8*)(xhA + aoff + s*32);
    s16x8 b0 = *(const s16x8*)(bp0 + s*512);
    s16x8 b1 = *(const s16x8*)(bp0 + 4096 + s*512);
    acc0 = __builtin_amdgcn_mfma_f32_16x16x32_bf16(a, b0, acc0, 0, 0, 0);
    acc1 = __builtin_amdgcn_mfma_f32_16x16x32_bf16(a, b1, acc1, 0, 0, 0);
  }
  // fold lo-product rows (8-15, lanes +32) into hi rows (0-7, lanes 0-31)
  #pragma unroll
  for (int v=0; v<4; v++){
    float l0 = __shfl_down(acc0[v], 32);
    float l1 = __shfl_down(acc1[v], 32);
    acc0[v] += l0;
    acc1[v] += l1;
  }
  if (kgrp < 2){
    int rb = kgrp*4;
    int c0g = n0*16 + mrow, c1g = c0g + 16;
    float bv0 = bl[c0g], bv1 = bl[c1g];
    #pragma unroll
    for (int v=0; v<4; v++){
      gates[(rb+v)*G4 + c0g] = acc0[v] + bv0;
      gates[(rb+v)*G4 + c1g] = acc1[v] + bv1;
    }
  }
}

__device__ __forceinline__ void activate(const float* __restrict__ gates,
                                         float* __restrict__ h, float* __restrict__ c, int tid)
{
  int r = tid >> 7, j = tid & 127;       // 1024 threads = 8 rows x 128
  const float* g = gates + r*G4;
  float ig = sigm (g[j]);
  float fg = sigm (g[j + Hn]);
  float gg = tanh_(g[j + 2*Hn]);
  float og = sigm (g[j + 3*Hn]);
  int hi = r*Hn + j;
  float cn = fg*c[hi] + ig*gg;
  c[hi] = cn;
  h[hi] = og*tanh_(cn);
}

// builders: write hi/lo rows of xhA. 1024 threads: k=tid&255, r=(tid>>8)+4*it.
__device__ __forceinline__ void build_src(u16* __restrict__ xhA,
                                          const float* __restrict__ src,
                                          long b0, int t, const float* __restrict__ h0, int tid)
{
  int k = tid & 255;
  #pragma unroll
  for (int it=0; it<2; it++){
    int r = (tid >> 8) + it*4;
    if (k < 192){
      float v;
      if (k < Dn) v = src[((size_t)(b0+r)*Tn + t)*Dn + k];
      else if (k < Dn + Hn) v = h0[r*Hn + (k - Dn)];
      else v = 0.f;
      wr_xh(xhA, r, k, v);
    }
  }
}

__device__ __forceinline__ void build_pred(u16* __restrict__ xhA,
                                           const float* __restrict__ pred,
                                           const float* __restrict__ h0, int tid)
{
  int k = tid & 255;
  #pragma unroll
  for (int it=0; it<2; it++){
    int r = (tid >> 8) + it*4;
    if (k < 192){
      float v;
      if (k < Dn) v = pred[r*64 + k];
      else if (k < Dn + Hn) v = h0[r*Hn + (k - Dn)];
      else v = 0.f;
      wr_xh(xhA, r, k, v);
    }
  }
}

__device__ __forceinline__ void build_mid(u16* __restrict__ xhA,
                                          const float* __restrict__ hlow,
                                          const float* __restrict__ hl, int tid)
{
  int k = tid & 255;
  #pragma unroll
  for (int it=0; it<2; it++){
    int r = (tid >> 8) + it*4;
    float v = (k < Hn) ? hlow[r*Hn + k] : hl[r*Hn + (k - Hn)];
    wr_xh(xhA, r, k, v);
  }
}

// OUTPUT IS FP32. 8 rows x 64 cols = 512 work items.
__device__ __forceinline__ void proj_out(const float* __restrict__ h2, const float* __restrict__ fwt,
                                         const float* __restrict__ fbw, float* __restrict__ pred,
                                         float* __restrict__ out, long b0, int t, int tid)
{
  if (tid < 512){
    int r = tid >> 6, d = tid & 63;
    const float* h = h2 + r*Hn;
    float acc = 0.f;
    #pragma unroll 8
    for (int k=0;k<Hn;k++) acc += h[k] * fwt[k*64 + d];
    if (d < Dn){
      float pv = acc + fbw[d];
      pred[r*64 + d] = pv;
      out[((size_t)(b0+r)*Tn + (Tn-1-t))*Dn + d] = pv;
    }
  }
}

// (1024, 4): 4 waves/EU -> VGPR cap ~128. Grid is 1 WG/CU; default 2-block
// targeting caused R9's 10.3 GB spill storm.
__global__ __launch_bounds__(NTH, 4) void lstm_kernel(
    const float* __restrict__ src, const u16* __restrict__ wsw,
    const float* __restrict__ bias, const float* __restrict__ fwt,
    const float* __restrict__ fbw, float* __restrict__ out)
{
  __shared__ __align__(16) u16   xhA[16*RP];      // 8.25 KB bf16: rows 0-7 hi, 8-15 lo
  __shared__ __align__(16) float gates[BR*G4];    // 16 KB
  __shared__ __align__(16) float hS[3*BR*Hn];     // 12 KB
  __shared__ __align__(16) float cS[3*BR*Hn];     // 12 KB
  __shared__ __align__(16) float pred[BR*64];     // 2 KB

  const int tid = threadIdx.x;
  const long b0 = (long)blockIdx.x * BR;

  for (int i=tid; i<16*RP; i+=NTH) xhA[i]=0;      // pads stay 0
  for (int i=tid; i<3*BR*Hn; i+=NTH){ hS[i]=0.f; cS[i]=0.f; }
  __syncthreads();

  // ---------------- encoder ----------------
  for (int t=0;t<Tn;t++){
    build_src(xhA, src, b0, t, hS, tid);
    __syncthreads();
    gemm_mfma<6>(wsw + 0*131072, bias + 0*G4, xhA, gates, tid);
    __syncthreads();
    activate(gates, hS, cS, tid);
    __syncthreads();

    build_mid(xhA, hS, hS + BR*Hn, tid);
    __syncthreads();
    gemm_mfma<8>(wsw + 1*131072, bias + 1*G4, xhA, gates, tid);
    __syncthreads();
    activate(gates, hS + BR*Hn, cS + BR*Hn, tid);
    __syncthreads();

    build_mid(xhA, hS + BR*Hn, hS + 2*BR*Hn, tid);
    __syncthreads();
    gemm_mfma<8>(wsw + 2*131072, bias + 2*G4, xhA, gates, tid);
    __syncthreads();
    activate(gates, hS + 2*BR*Hn, cS + 2*BR*Hn, tid);
    __syncthreads();
  }

  // ---------------- decoder ----------------
  if (tid < 512) pred[tid] = 0.f;
  __syncthreads();

  for (int t=0;t<Tn;t++){
    build_pred(xhA, pred, hS, tid);
    __syncthreads();
    gemm_mfma<6>(wsw + 3*131072, bias + 3*G4, xhA, gates, tid);
    __syncthreads();
    activate(gates, hS, cS, tid);
    __syncthreads();

    build_mid(xhA, hS, hS + BR*Hn, tid);
    __syncthreads();
    gemm_mfma<8>(wsw + 4*131072, bias + 4*G4, xhA, gates, tid);
    __syncthreads();
    activate(gates, hS + BR*Hn, cS + BR*Hn, tid);
    __syncthreads();

    build_mid(xhA, hS + BR*Hn, hS + 2*BR*Hn, tid);
    __syncthreads();
    gemm_mfma<8>(wsw + 5*131072, bias + 5*G4, xhA, gates, tid);
    __syncthreads();
    activate(gates, hS + 2*BR*Hn, cS + 2*BR*Hn, tid);
    __syncthreads();

    proj_out(hS + 2*BR*Hn, fwt, fbw, pred, out, b0, t, tid);
    __syncthreads();
  }
}

extern "C" void kernel_launch(void* const* d_in, const int* in_sizes, int n_in,
                              void* d_out, int out_size, void* d_ws, size_t ws_size,
                              hipStream_t stream)
{
  (void)in_sizes; (void)n_in; (void)out_size; (void)ws_size;
  const float* src = (const float*)d_in[0];
  WP p;
  for (int l=0;l<3;l++){
    p.W[l]    = (const float*)d_in[1  + 3*l];
    p.U[l]    = (const float*)d_in[2  + 3*l];
    p.Bb[l]   = (const float*)d_in[3  + 3*l];
    p.W[3+l]  = (const float*)d_in[10 + 3*l];
    p.U[3+l]  = (const float*)d_in[11 + 3*l];
    p.Bb[3+l] = (const float*)d_in[12 + 3*l];
  }
  p.fW = (const float*)d_in[19];
  p.fb = (const float*)d_in[20];

  // ws: wsw u16[786432] (1.5MB) | bias f32[3072] | fwt f32[8192] | fbw f32[64]
  u16*   wsw  = (u16*)d_ws;
  float* bias = (float*)((char*)d_ws + 6*131072*sizeof(u16));
  float* fwt  = bias + 6*512;
  float* fbw  = fwt + 8192;

  prep_kernel<<<(PREP_TOTAL + 255)/256, 256, 0, stream>>>(p, wsw, bias, fwt, fbw);
  lstm_kernel<<<NWG, NTH, 0, stream>>>(src, wsw, bias, fwt, fbw, (float*)d_out);
}

// Round 12
// 2051.799 us; speedup vs baseline: 3.2041x; 3.2041x over previous
//
#include <hip/hip_runtime.h>
#include <stdint.h>

#define Tn 100
#define Dn 51
#define Hn 128
#define G4 512     // 4*H
#define BR 8       // batch rows per workgroup
#define NWG 256    // workgroups (2048 / 8)
#define NTH 1024   // 16 waves
#define RP 264     // xhA row stride in bf16 elems (16B-aligned rows)

typedef unsigned int uint32;
typedef unsigned short u16;
typedef short s16x8 __attribute__((ext_vector_type(8)));   // 8 bf16 = 4 VGPRs
typedef float f32x4v __attribute__((ext_vector_type(4)));

__device__ __forceinline__ float rcp_(float x){ return __builtin_amdgcn_rcpf(x); }
__device__ __forceinline__ float sigm(float x){ return rcp_(1.f + __expf(-x)); }
__device__ __forceinline__ float tanh_(float x){ return 1.f - 2.f*rcp_(1.f + __expf(2.f*x)); }

// fp32 -> bf16 round-to-nearest-even
__device__ __forceinline__ u16 f2bf(float f){
  uint32 u = __float_as_uint(f);
  return (u16)((u + 0x7fffu + ((u >> 16) & 1u)) >> 16);
}
__device__ __forceinline__ float bf2f(u16 u){ return __uint_as_float(((uint32)u)<<16); }

// A-fragment trick: row r (0..7) = bf16-hi of xh row r; row r+8 = bf16-lo.
// One MFMA computes both pumps; epilogue sums D[r] + D[r+8] via shfl.
__device__ __forceinline__ void wr_xh(u16* __restrict__ xhA, int r, int k, float v){
  u16 h = f2bf(v);
  xhA[r*RP + k]     = h;
  xhA[(r+8)*RP + k] = f2bf(v - bf2f(h));
}

struct WP {
  const float* W[6];   // [4H, din]  enc0..2, dec0..2 (fp32)
  const float* U[6];   // [4H, H]
  const float* Bb[6];  // [4H]
  const float* fW;     // [D, H]
  const float* fb;     // [D]
};

// ws: wsw = MFMA-B-fragment-swizzled bf16 weights.
// Layout per layer (uniform 131072 u16): block (n,s) at ((n*8+s)*64+lane)*8+j,
// holding Wc[k = s*32+(lane>>4)*8+j][c = n*16+(lane&15)], Wc = [Wih | Whh] along k,
// zero-padded (k>=K or s>=S). A wave's B-frag load = contiguous 1KB dwordx4.
#define PREP_TOTAL (6*131072 + 6*512 + 8192 + 64)
__global__ void prep_kernel(WP p, u16* __restrict__ wsw, float* __restrict__ bias,
                            float* __restrict__ fwt, float* __restrict__ fbw)
{
  int gid = blockIdx.x*256 + threadIdx.x;
  if (gid >= PREP_TOTAL) return;
  if (gid < 6*131072){
    int l = gid >> 17;
    int e = gid & 131071;
    int n    = e >> 12;
    int s    = (e >> 9) & 7;
    int lane = (e >> 3) & 63;
    int j    = e & 7;
    int k = s*32 + (lane >> 4)*8 + j;
    int c = n*16 + (lane & 15);
    int din = (l % 3 == 0) ? Dn : Hn;
    int K = din + Hn;
    u16 v = 0;
    if (k < K){
      float f = (k < din) ? p.W[l][(size_t)c*din + k] : p.U[l][(size_t)c*Hn + (k - din)];
      v = f2bf(f);
    }
    wsw[gid] = v;
  } else if (gid < 6*131072 + 6*512){
    int i = gid - 6*131072;
    bias[i] = p.Bb[i>>9][i & 511];
  } else if (gid < 6*131072 + 6*512 + 8192){
    int i = gid - (6*131072 + 6*512);
    int k = i >> 6, d = i & 63;
    fwt[i] = (d < Dn) ? p.fW[(size_t)d*Hn + k] : 0.f;
  } else {
    int d = gid - (6*131072 + 6*512 + 8192);
    fbw[d] = (d < Dn) ? p.fb[d] : 0.f;
  }
}

// gates[r][c] = bias[c] + sum_k xh[r][k]*Wc[k][c] via mfma_f32_16x16x32_bf16.
// Wave w owns N-tiles n=2w,2w+1. A rows 0-7 = hi, 8-15 = lo (one MFMA/both pumps).
// C/D: col=lane&15, row=(lane>>4)*4+reg (m89) -> row r in lane L<32, r+8 in L+32.
// NOTE: unroll 2, NOT full — full unroll (R11) pushed pressure past the 64-VGPR
// tier and the allocator spilled 9.5 GB of scratch instead of using 128 VGPRs.
template<int S>
__device__ __forceinline__ void gemm_mfma(const u16* __restrict__ wsl,
                                          const float* __restrict__ bl,
                                          const u16* __restrict__ xhA,
                                          float* __restrict__ gates, int tid)
{
  const int wave = tid >> 6, lane = tid & 63;
  const int mrow = lane & 15, kgrp = lane >> 4;
  const int n0 = wave*2;
  const u16* bp0 = wsl + n0*4096 + lane*8;
  const int aoff = mrow*RP + kgrp*8;
  f32x4v acc0 = {0.f,0.f,0.f,0.f}, acc1 = {0.f,0.f,0.f,0.f};
  #pragma unroll 2
  for (int s=0; s<S; s++){
    s16x8 a  = *(const s16x8*)(xhA + aoff + s*32);
    s16x8 b0 = *(const s16x8*)(bp0 + s*512);
    s16x8 b1 = *(const s16x8*)(bp0 + 4096 + s*512);
    acc0 = __builtin_amdgcn_mfma_f32_16x16x32_bf16(a, b0, acc0, 0, 0, 0);
    acc1 = __builtin_amdgcn_mfma_f32_16x16x32_bf16(a, b1, acc1, 0, 0, 0);
  }
  // fold lo-product rows (8-15, lanes +32) into hi rows (0-7, lanes 0-31)
  #pragma unroll
  for (int v=0; v<4; v++){
    float l0 = __shfl_down(acc0[v], 32);
    float l1 = __shfl_down(acc1[v], 32);
    acc0[v] += l0;
    acc1[v] += l1;
  }
  if (kgrp < 2){
    int rb = kgrp*4;
    int c0g = n0*16 + mrow, c1g = c0g + 16;
    float bv0 = bl[c0g], bv1 = bl[c1g];
    #pragma unroll
    for (int v=0; v<4; v++){
      gates[(rb+v)*G4 + c0g] = acc0[v] + bv0;
      gates[(rb+v)*G4 + c1g] = acc1[v] + bv1;
    }
  }
}

__device__ __forceinline__ void activate(const float* __restrict__ gates,
                                         float* __restrict__ h, float* __restrict__ c, int tid)
{
  int r = tid >> 7, j = tid & 127;       // 1024 threads = 8 rows x 128
  const float* g = gates + r*G4;
  float ig = sigm (g[j]);
  float fg = sigm (g[j + Hn]);
  float gg = tanh_(g[j + 2*Hn]);
  float og = sigm (g[j + 3*Hn]);
  int hi = r*Hn + j;
  float cn = fg*c[hi] + ig*gg;
  c[hi] = cn;
  h[hi] = og*tanh_(cn);
}

// builders: write hi/lo rows of xhA. 1024 threads: k=tid&255, r=(tid>>8)+4*it.
__device__ __forceinline__ void build_src(u16* __restrict__ xhA,
                                          const float* __restrict__ src,
                                          long b0, int t, const float* __restrict__ h0, int tid)
{
  int k = tid & 255;
  #pragma unroll
  for (int it=0; it<2; it++){
    int r = (tid >> 8) + it*4;
    if (k < 192){
      float v;
      if (k < Dn) v = src[((size_t)(b0+r)*Tn + t)*Dn + k];
      else if (k < Dn + Hn) v = h0[r*Hn + (k - Dn)];
      else v = 0.f;
      wr_xh(xhA, r, k, v);
    }
  }
}

__device__ __forceinline__ void build_pred(u16* __restrict__ xhA,
                                           const float* __restrict__ pred,
                                           const float* __restrict__ h0, int tid)
{
  int k = tid & 255;
  #pragma unroll
  for (int it=0; it<2; it++){
    int r = (tid >> 8) + it*4;
    if (k < 192){
      float v;
      if (k < Dn) v = pred[r*64 + k];
      else if (k < Dn + Hn) v = h0[r*Hn + (k - Dn)];
      else v = 0.f;
      wr_xh(xhA, r, k, v);
    }
  }
}

__device__ __forceinline__ void build_mid(u16* __restrict__ xhA,
                                          const float* __restrict__ hlow,
                                          const float* __restrict__ hl, int tid)
{
  int k = tid & 255;
  #pragma unroll
  for (int it=0; it<2; it++){
    int r = (tid >> 8) + it*4;
    float v = (k < Hn) ? hlow[r*Hn + k] : hl[r*Hn + (k - Hn)];
    wr_xh(xhA, r, k, v);
  }
}

// OUTPUT IS FP32. 8 rows x 64 cols = 512 work items.
__device__ __forceinline__ void proj_out(const float* __restrict__ h2, const float* __restrict__ fwt,
                                         const float* __restrict__ fbw, float* __restrict__ pred,
                                         float* __restrict__ out, long b0, int t, int tid)
{
  if (tid < 512){
    int r = tid >> 6, d = tid & 63;
    const float* h = h2 + r*Hn;
    float acc = 0.f;
    #pragma unroll 8
    for (int k=0;k<Hn;k++) acc += h[k] * fwt[k*64 + d];
    if (d < Dn){
      float pv = acc + fbw[d];
      pred[r*64 + d] = pv;
      out[((size_t)(b0+r)*Tn + (Tn-1-t))*Dn + d] = pv;
    }
  }
}

// (1024, 4): 4 waves/EU -> VGPR cap ~128. Grid is 1 WG/CU; default 2-block
// targeting caused R9's 10.3 GB spill storm.
__global__ __launch_bounds__(NTH, 4) void lstm_kernel(
    const float* __restrict__ src, const u16* __restrict__ wsw,
    const float* __restrict__ bias, const float* __restrict__ fwt,
    const float* __restrict__ fbw, float* __restrict__ out)
{
  __shared__ __align__(16) u16   xhA[16*RP];      // 8.25 KB bf16: rows 0-7 hi, 8-15 lo
  __shared__ __align__(16) float gates[BR*G4];    // 16 KB
  __shared__ __align__(16) float hS[3*BR*Hn];     // 12 KB
  __shared__ __align__(16) float cS[3*BR*Hn];     // 12 KB
  __shared__ __align__(16) float pred[BR*64];     // 2 KB

  const int tid = threadIdx.x;
  const long b0 = (long)blockIdx.x * BR;

  for (int i=tid; i<16*RP; i+=NTH) xhA[i]=0;      // pads stay 0
  for (int i=tid; i<3*BR*Hn; i+=NTH){ hS[i]=0.f; cS[i]=0.f; }
  __syncthreads();

  // ---------------- encoder ----------------
  for (int t=0;t<Tn;t++){
    build_src(xhA, src, b0, t, hS, tid);
    __syncthreads();
    gemm_mfma<6>(wsw + 0*131072, bias + 0*G4, xhA, gates, tid);
    __syncthreads();
    activate(gates, hS, cS, tid);
    __syncthreads();

    build_mid(xhA, hS, hS + BR*Hn, tid);
    __syncthreads();
    gemm_mfma<8>(wsw + 1*131072, bias + 1*G4, xhA, gates, tid);
    __syncthreads();
    activate(gates, hS + BR*Hn, cS + BR*Hn, tid);
    __syncthreads();

    build_mid(xhA, hS + BR*Hn, hS + 2*BR*Hn, tid);
    __syncthreads();
    gemm_mfma<8>(wsw + 2*131072, bias + 2*G4, xhA, gates, tid);
    __syncthreads();
    activate(gates, hS + 2*BR*Hn, cS + 2*BR*Hn, tid);
    __syncthreads();
  }

  // ---------------- decoder ----------------
  if (tid < 512) pred[tid] = 0.f;
  __syncthreads();

  for (int t=0;t<Tn;t++){
    build_pred(xhA, pred, hS, tid);
    __syncthreads();
    gemm_mfma<6>(wsw + 3*131072, bias + 3*G4, xhA, gates, tid);
    __syncthreads();
    activate(gates, hS, cS, tid);
    __syncthreads();

    build_mid(xhA, hS, hS + BR*Hn, tid);
    __syncthreads();
    gemm_mfma<8>(wsw + 4*131072, bias + 4*G4, xhA, gates, tid);
    __syncthreads();
    activate(gates, hS + BR*Hn, cS + BR*Hn, tid);
    __syncthreads();

    build_mid(xhA, hS + BR*Hn, hS + 2*BR*Hn, tid);
    __syncthreads();
    gemm_mfma<8>(wsw + 5*131072, bias + 5*G4, xhA, gates, tid);
    __syncthreads();
    activate(gates, hS + 2*BR*Hn, cS + 2*BR*Hn, tid);
    __syncthreads();

    proj_out(hS + 2*BR*Hn, fwt, fbw, pred, out, b0, t, tid);
    __syncthreads();
  }
}

extern "C" void kernel_launch(void* const* d_in, const int* in_sizes, int n_in,
                              void* d_out, int out_size, void* d_ws, size_t ws_size,
                              hipStream_t stream)
{
  (void)in_sizes; (void)n_in; (void)out_size; (void)ws_size;
  const float* src = (const float*)d_in[0];
  WP p;
  for (int l=0;l<3;l++){
    p.W[l]    = (const float*)d_in[1  + 3*l];
    p.U[l]    = (const float*)d_in[2  + 3*l];
    p.Bb[l]   = (const float*)d_in[3  + 3*l];
    p.W[3+l]  = (const float*)d_in[10 + 3*l];
    p.U[3+l]  = (const float*)d_in[11 + 3*l];
    p.Bb[3+l] = (const float*)d_in[12 + 3*l];
  }
  p.fW = (const float*)d_in[19];
  p.fb = (const float*)d_in[20];

  // ws: wsw u16[786432] (1.5MB) | bias f32[3072] | fwt f32[8192] | fbw f32[64]
  u16*   wsw  = (u16*)d_ws;
  float* bias = (float*)((char*)d_ws + 6*131072*sizeof(u16));
  float* fwt  = bias + 6*512;
  float* fbw  = fwt + 8192;

  prep_kernel<<<(PREP_TOTAL + 255)/256, 256, 0, stream>>>(p, wsw, bias, fwt, fbw);
  lstm_kernel<<<NWG, NTH, 0, stream>>>(src, wsw, bias, fwt, fbw, (float*)d_out);
}